// Round 14
// baseline (352.271 us; speedup 1.0000x reference)
//
#include <hip/hip_runtime.h>

typedef short s16x8 __attribute__((ext_vector_type(8)));
typedef float f32x4 __attribute__((ext_vector_type(4)));

#define MFMA16(a, b, c) __builtin_amdgcn_mfma_f32_16x16x32_bf16((a), (b), (c), 0, 0, 0)

__device__ __forceinline__ unsigned short f2b(float f) {
  union { float f; unsigned int u; } v; v.f = f;
  unsigned int u = v.u;
  unsigned int r = (u + 0x7fffu + ((u >> 16) & 1u)) >> 16;  // RNE
  return (unsigned short)r;
}
__device__ __forceinline__ float b2f(unsigned short b) {
  union { unsigned int u; float f; } v; v.u = ((unsigned int)b) << 16;
  return v.f;
}

__device__ __forceinline__ void gld_lds16(const void* g, void* l) {
  __builtin_amdgcn_global_load_lds(
      (const __attribute__((address_space(1))) unsigned int*)g,
      (__attribute__((address_space(3))) unsigned int*)l, 16, 0, 0);
}

// ---------------- prep ----------------
__global__ __launch_bounds__(256) void cvt_x(const float* __restrict__ x,
                                             unsigned short* __restrict__ xb) {
  size_t i = ((size_t)blockIdx.x * 256 + threadIdx.x) * 4;
  float4 v = *(const float4*)(x + i);
  ushort4 o;
  o.x = f2b(v.x); o.y = f2b(v.y); o.z = f2b(v.z); o.w = f2b(v.w);
  *(ushort4*)(xb + i) = o;
}

// WcatT[n][k] = W[k][n], n in [0,3072): [wq | wkv | hq | hkv]
__global__ __launch_bounds__(256) void build_wt(const float* __restrict__ wq,
                                                const float* __restrict__ wkv,
                                                const float* __restrict__ hq,
                                                const float* __restrict__ hkv,
                                                unsigned short* __restrict__ WT) {
  const int n = blockIdx.x, k = threadIdx.x;
  float v;
  if (n < 512)       v = wq [(size_t)k * 512  + n];
  else if (n < 1536) v = wkv[(size_t)k * 1024 + (n - 512)];
  else if (n < 2048) v = hq [(size_t)k * 512  + (n - 1536)];
  else               v = hkv[(size_t)k * 1024 + (n - 2048)];
  WT[(size_t)n * 256 + k] = f2b(v);
}

// W2T[n][k] = [wout;hout][k][n], n<256, k<1024
__global__ __launch_bounds__(256) void build_w2t(const float* __restrict__ wout,
                                                 const float* __restrict__ hout,
                                                 unsigned short* __restrict__ W2T) {
  const int n = blockIdx.x;
  for (int k = threadIdx.x; k < 1024; k += 256) {
    const float v = (k < 512) ? wout[(size_t)k * 256 + n] : hout[(size_t)(k - 512) * 256 + n];
    W2T[(size_t)n * 1024 + k] = f2b(v);
  }
}

// ---------------- merged QKV projection, BOTH branches in one dispatch ----------------
// 6144 blocks, 512 threads (8 light waves, r12 structure).  XCD chunk: xcd owns
// 32 m-panels x 24 n-tiles (m fastest) -> X chunk (2 MB) + all of WcatT L2-hot.
// n in [0,1536) -> branch 0 (col layout) into C0; n in [1536,3072) -> branch 1 into C1.
__global__ __launch_bounds__(512) void gemm_qkv2(const unsigned short* __restrict__ X,
                                                 const unsigned short* __restrict__ WT,
                                                 unsigned short* __restrict__ C0,
                                                 unsigned short* __restrict__ C1) {
  __shared__ unsigned short As[128 * 32];
  __shared__ unsigned short Bs[128 * 32];
  const int tid = threadIdx.x, wave = tid >> 6, lane = tid & 63;
  const int q = lane >> 4, l = lane & 15;
  const int xcd = blockIdx.x & 7;
  const int c = blockIdx.x >> 3;                  // 0..767 within XCD chunk
  const int m0 = (xcd * 32 + (c & 31)) * 128;     // m fastest within chunk
  const int n0 = (c >> 5) * 128;                  // 24 n-tiles (both branches)
  const int mt = (wave >> 1) * 32;                // 4x2 wave grid, 32x64 tiles
  const int nt = (wave & 1) * 64;
  const char* Xb = (const char*)X;
  const char* Wb = (const char*)WT;
  const int srow = tid >> 2;                      // staging row (0..127)
  const int sboff = (tid & 3) * 16;
  char* AsB = (char*)As;
  char* BsB = (char*)Bs;
  f32x4 acc[2][4] = {};
#pragma unroll
  for (int ks = 0; ks < 8; ++ks) {
    const int kb = ks * 64;
    gld_lds16(Xb + (size_t)(m0 + srow) * 512 + kb + sboff, AsB + tid * 16);
    gld_lds16(Wb + (size_t)(n0 + srow) * 512 + kb + sboff, BsB + tid * 16);
    __syncthreads();
    s16x8 a[2], b[4];
#pragma unroll
    for (int i = 0; i < 2; ++i) a[i] = *(const s16x8*)(&As[(mt + i * 16 + l) * 32 + q * 8]);
#pragma unroll
    for (int j = 0; j < 4; ++j) b[j] = *(const s16x8*)(&Bs[(nt + j * 16 + l) * 32 + q * 8]);
#pragma unroll
    for (int i = 0; i < 2; ++i)
#pragma unroll
      for (int j = 0; j < 4; ++j) acc[i][j] = MFMA16(b[j], a[i], acc[i][j]);  // swapped: D^T
    __syncthreads();
  }
  const int br = (n0 >= 1536);  // block-uniform
#pragma unroll
  for (int i = 0; i < 2; ++i) {
    const int m = m0 + mt + i * 16 + l;
    const int mrow = (br == 0) ? ((m & 255) * 8) : ((m >> 8) * 8);
    const int mcol = (br == 0) ? (m >> 8) : (m & 255);
    const int mdim = (br == 0) ? 128 : 256;
#pragma unroll
    for (int j = 0; j < 4; ++j) {
      const int nn = n0 + nt + j * 16 + q * 4 - br * 1536;  // 0..1535 within branch
      const int part = nn >> 9, H = (nn & 511) >> 6, d = nn & 63;
      ushort4 o;
      o.x = f2b(acc[i][j][0]); o.y = f2b(acc[i][j][1]);
      o.z = f2b(acc[i][j][2]); o.w = f2b(acc[i][j][3]);
      unsigned short* base = (br ? C1 : C0) + (size_t)part * 16777216;
      const size_t idx = ((size_t)(mrow + H) * mdim + mcol) * 64 + d;
      *(ushort4*)(base + idx) = o;
    }
  }
}

// ---------------- single-branch QKV projection (fallback, r13) ----------------
__global__ __launch_bounds__(512) void gemm_qkv(const unsigned short* __restrict__ X,
                                                const unsigned short* __restrict__ WT,
                                                unsigned short* __restrict__ C,
                                                int branch) {
  __shared__ unsigned short As[128 * 32];
  __shared__ unsigned short Bs[128 * 32];
  const int tid = threadIdx.x, wave = tid >> 6, lane = tid & 63;
  const int q = lane >> 4, l = lane & 15;
  const int xcd = blockIdx.x & 7;
  const int c = blockIdx.x >> 3;
  const int m0 = (xcd * 32 + (c & 31)) * 128;
  const int n0 = (c >> 5) * 128;
  const int mt = (wave >> 1) * 32;
  const int nt = (wave & 1) * 64;
  const char* Xb = (const char*)X;
  const char* Wb = (const char*)WT;
  const int srow = tid >> 2;
  const int sboff = (tid & 3) * 16;
  char* AsB = (char*)As;
  char* BsB = (char*)Bs;
  f32x4 acc[2][4] = {};
#pragma unroll
  for (int ks = 0; ks < 8; ++ks) {
    const int kb = ks * 64;
    gld_lds16(Xb + (size_t)(m0 + srow) * 512 + kb + sboff, AsB + tid * 16);
    gld_lds16(Wb + (size_t)(n0 + srow) * 512 + kb + sboff, BsB + tid * 16);
    __syncthreads();
    s16x8 a[2], b[4];
#pragma unroll
    for (int i = 0; i < 2; ++i) a[i] = *(const s16x8*)(&As[(mt + i * 16 + l) * 32 + q * 8]);
#pragma unroll
    for (int j = 0; j < 4; ++j) b[j] = *(const s16x8*)(&Bs[(nt + j * 16 + l) * 32 + q * 8]);
#pragma unroll
    for (int i = 0; i < 2; ++i)
#pragma unroll
      for (int j = 0; j < 4; ++j) acc[i][j] = MFMA16(b[j], a[i], acc[i][j]);  // swapped: D^T
    __syncthreads();
  }
#pragma unroll
  for (int i = 0; i < 2; ++i) {
    const int m = m0 + mt + i * 16 + l;
    const int mrow = (branch == 0) ? ((m & 255) * 8) : ((m >> 8) * 8);
    const int mcol = (branch == 0) ? (m >> 8) : (m & 255);
    const int mdim = (branch == 0) ? 128 : 256;
#pragma unroll
    for (int j = 0; j < 4; ++j) {
      const int n = n0 + nt + j * 16 + q * 4;
      const int part = n >> 9, H = (n & 511) >> 6, d = n & 63;
      ushort4 o;
      o.x = f2b(acc[i][j][0]); o.y = f2b(acc[i][j][1]);
      o.z = f2b(acc[i][j][2]); o.w = f2b(acc[i][j][3]);
      unsigned short* base = C + (size_t)part * 16777216;
      const size_t idx = ((size_t)(mrow + H) * mdim + mcol) * 64 + d;
      *(ushort4*)(base + idx) = o;
    }
  }
}

// ---------------- column attention: one block per (w, H)  (r13, verified) ----------------
__global__ __launch_bounds__(256) void col_attn(const unsigned short* __restrict__ C,
                                                unsigned short* __restrict__ O) {
  __shared__ __align__(16) char lds[50176];  // [0,32768): Q|K then Sp ; [32768,...): Vt
  char* QK = lds;
  unsigned short* Vt = (unsigned short*)(lds + 32768);  // [64][136]
  const int w = blockIdx.x, H = blockIdx.y;
  const int tid = threadIdx.x, wave = tid >> 6, lane = tid & 63;
  const int q = lane >> 4, l = lane & 15;
  const size_t slab = (size_t)(w * 8 + H) * 8192;  // 128x64
  const unsigned short* Qs = C + slab;
  const unsigned short* Ks = C + 16777216 + slab;
  const unsigned short* Vs = C + 33554432 + slab;
  // stage Q (16 KB) + K (16 KB): LDS chunk (r,c) <- global chunk (r, c^(r&7))
#pragma unroll
  for (int it = 0; it < 8; ++it) {
    const int u = it * 256 + tid;            // 0..2047 16B-chunks
    const int half = u >> 10;                // 0=Q, 1=K
    const int vv = u & 1023;
    const int r = vv >> 3, ch = vv & 7;      // row 0..127, chunk 0..7
    const char* src = (const char*)(half ? Ks : Qs);
    gld_lds16(src + (size_t)r * 128 + ((ch ^ (r & 7)) * 16), QK + u * 16);
  }
  // stage V^T: Vt[d][j] = V[j][d]
  for (int u = tid; u < 1024; u += 256) {
    const int j = u >> 3, db = u & 7;
    s16x8 v = *(const s16x8*)(Vs + j * 64 + db * 8);
#pragma unroll
    for (int t = 0; t < 8; ++t) Vt[(db * 8 + t) * 136 + j] = v[t];
  }
  __syncthreads();  // Q,K,Vt ready
  const int m0 = wave * 32;
  f32x4 acc[2][8] = {};
#pragma unroll
  for (int ks = 0; ks < 2; ++ks) {
    s16x8 a[2], b[8];
#pragma unroll
    for (int i = 0; i < 2; ++i) {
      const int ra = m0 + i * 16 + l;
      a[i] = *(const s16x8*)(QK + (size_t)ra * 128 + (((ks * 4 + q) ^ (ra & 7)) * 16));
    }
#pragma unroll
    for (int j = 0; j < 8; ++j) {
      const int rb = j * 16 + l;
      b[j] = *(const s16x8*)(QK + 16384 + (size_t)rb * 128 + (((ks * 4 + q) ^ (rb & 7)) * 16));
    }
#pragma unroll
    for (int i = 0; i < 2; ++i)
#pragma unroll
      for (int j = 0; j < 8; ++j) acc[i][j] = MFMA16(a[i], b[j], acc[i][j]);
  }
  __syncthreads();  // all waves done reading Q/K -> region becomes Sp
#pragma unroll
  for (int i = 0; i < 2; ++i)
#pragma unroll
    for (int r = 0; r < 4; ++r) {
      float v[8];
#pragma unroll
      for (int j = 0; j < 8; ++j) v[j] = acc[i][j][r] * 0.125f;
      float mx = fmaxf(fmaxf(fmaxf(v[0], v[1]), fmaxf(v[2], v[3])),
                       fmaxf(fmaxf(v[4], v[5]), fmaxf(v[6], v[7])));
      mx = fmaxf(mx, __shfl_xor(mx, 1));
      mx = fmaxf(mx, __shfl_xor(mx, 2));
      mx = fmaxf(mx, __shfl_xor(mx, 4));
      mx = fmaxf(mx, __shfl_xor(mx, 8));
      float s = 0.f;
#pragma unroll
      for (int j = 0; j < 8; ++j) { v[j] = __expf(v[j] - mx); s += v[j]; }
      s += __shfl_xor(s, 1);
      s += __shfl_xor(s, 2);
      s += __shfl_xor(s, 4);
      s += __shfl_xor(s, 8);
      const float inv = 1.0f / s;
      const int row = m0 + i * 16 + q * 4 + r;
#pragma unroll
      for (int j = 0; j < 8; ++j) {
        const int ch = 2 * j + (l >> 3);  // 16B chunk of col j*16+l
        *(unsigned short*)(QK + (size_t)row * 256 + ((ch ^ (row & 7)) * 16) + (l & 7) * 2) =
            f2b(v[j] * inv);
      }
    }
  // Sp rows are wave-private; Vt covered by first barrier.
  f32x4 o[2][4] = {};
#pragma unroll
  for (int ks = 0; ks < 4; ++ks) {
    const int kk = ks * 32 + q * 8;
    s16x8 a[2], b[4];
#pragma unroll
    for (int i = 0; i < 2; ++i) {
      const int ra = m0 + i * 16 + l;
      a[i] = *(const s16x8*)(QK + (size_t)ra * 256 + (((ks * 4 + q) ^ (ra & 7)) * 16));
    }
#pragma unroll
    for (int j = 0; j < 4; ++j) b[j] = *(const s16x8*)(&Vt[(j * 16 + l) * 136 + kk]);
#pragma unroll
    for (int i = 0; i < 2; ++i)
#pragma unroll
      for (int j = 0; j < 4; ++j) o[i][j] = MFMA16(a[i], b[j], o[i][j]);
  }
#pragma unroll
  for (int i = 0; i < 2; ++i)
#pragma unroll
    for (int j = 0; j < 4; ++j)
#pragma unroll
      for (int r = 0; r < 4; ++r) {
        const int row = m0 + i * 16 + q * 4 + r;  // seq pos (h index)
        const int d = j * 16 + l;
        O[(size_t)(row * 256 + w) * 1024 + H * 64 + d] = f2b(o[i][j][r]);
      }
}

// ---------------- tied row attention dots, split-K over 8 chunks of 16 rows ----------------
__global__ __launch_bounds__(256) void row_dots(const unsigned short* __restrict__ C,
                                                float* __restrict__ dp) {
  const int H = blockIdx.z;
  const int r0 = blockIdx.y * 16;
  const int ti = blockIdx.x & 1, tj = blockIdx.x >> 1;
  const int tid = threadIdx.x, wave = tid >> 6, lane = tid & 63;
  const int q = lane >> 4, l = lane & 15;
  const int m0 = ti * 128 + (wave >> 1) * 64;
  const int n0 = tj * 128 + (wave & 1) * 64;
  const unsigned short* Qh = C;
  const unsigned short* Kh = C + 16777216;
  f32x4 acc[4][4] = {};
  for (int ks = 0; ks < 32; ++ks) {
    const int k = ks * 32 + q * 8;
    const int rr = r0 + (k >> 6), d = k & 63;
    const size_t slab = (size_t)(rr * 8 + H) * 16384;  // 256x64
    s16x8 a[4], b[4];
#pragma unroll
    for (int i = 0; i < 4; ++i) a[i] = *(const s16x8*)(Qh + slab + (m0 + i * 16 + l) * 64 + d);
#pragma unroll
    for (int j = 0; j < 4; ++j) b[j] = *(const s16x8*)(Kh + slab + (n0 + j * 16 + l) * 64 + d);
#pragma unroll
    for (int i = 0; i < 4; ++i)
#pragma unroll
      for (int j = 0; j < 4; ++j) acc[i][j] = MFMA16(a[i], b[j], acc[i][j]);
  }
  float* outp = dp + ((size_t)blockIdx.y * 8 + H) * 65536;
#pragma unroll
  for (int i = 0; i < 4; ++i)
#pragma unroll
    for (int j = 0; j < 4; ++j)
#pragma unroll
      for (int r = 0; r < 4; ++r)
        outp[(size_t)(m0 + i * 16 + q * 4 + r) * 256 + n0 + j * 16 + l] = acc[i][j][r];
}

__global__ __launch_bounds__(256) void row_softmax(const float* __restrict__ dp,
                                                   unsigned short* __restrict__ attn) {
  const int row = blockIdx.x;  // H*256 + i
  const int H = row >> 8, i = row & 255;
  const int t = threadIdx.x, wave = t >> 6, lane = t & 63;
  __shared__ float red[8];
  float v = 0.f;
#pragma unroll
  for (int c = 0; c < 8; ++c) v += dp[((size_t)c * 8 + H) * 65536 + (size_t)i * 256 + t];
  v *= 1.1048543456e-2f;  // 0.125 / sqrt(128)
  float m = v;
  for (int o = 32; o > 0; o >>= 1) m = fmaxf(m, __shfl_xor(m, o, 64));
  if (lane == 0) red[wave] = m;
  __syncthreads();
  const float M = fmaxf(fmaxf(red[0], red[1]), fmaxf(red[2], red[3]));
  const float e = __expf(v - M);
  float s = e;
  for (int o = 32; o > 0; o >>= 1) s += __shfl_xor(s, o, 64);
  if (lane == 0) red[4 + wave] = s;
  __syncthreads();
  const float S = red[4] + red[5] + red[6] + red[7];
  attn[(size_t)row * 256 + t] = f2b(e / S);
}

// ---------------- row attention PV: one block per (r, H) ----------------
__global__ __launch_bounds__(256) void row_pv(const unsigned short* __restrict__ C,
                                              const unsigned short* __restrict__ attn,
                                              unsigned short* __restrict__ O) {
  __shared__ unsigned short Vt[64 * 264];
  const int r = blockIdx.x, H = blockIdx.y;
  const int tid = threadIdx.x, wave = tid >> 6, lane = tid & 63;
  const int q = lane >> 4, l = lane & 15;
  const unsigned short* Vs = C + 33554432 + (size_t)(r * 8 + H) * 16384;
  for (int u = tid; u < 2048; u += 256) {
    const int j = u >> 3, db = u & 7;
    s16x8 v = *(const s16x8*)(Vs + j * 64 + db * 8);
#pragma unroll
    for (int t = 0; t < 8; ++t) Vt[(db * 8 + t) * 264 + j] = v[t];
  }
  __syncthreads();
  const unsigned short* A = attn + (size_t)H * 65536;
  const int m0 = wave * 64;
  f32x4 acc[4][4] = {};
#pragma unroll
  for (int ks = 0; ks < 8; ++ks) {
    const int kk = ks * 32 + q * 8;
    s16x8 a[4], b[4];
#pragma unroll
    for (int i = 0; i < 4; ++i) a[i] = *(const s16x8*)(A + (size_t)(m0 + i * 16 + l) * 256 + kk);
#pragma unroll
    for (int j = 0; j < 4; ++j) b[j] = *(const s16x8*)(&Vt[(j * 16 + l) * 264 + kk]);
#pragma unroll
    for (int i = 0; i < 4; ++i)
#pragma unroll
      for (int j = 0; j < 4; ++j) acc[i][j] = MFMA16(a[i], b[j], acc[i][j]);
  }
#pragma unroll
  for (int i = 0; i < 4; ++i)
#pragma unroll
    for (int j = 0; j < 4; ++j)
#pragma unroll
      for (int rr = 0; rr < 4; ++rr) {
        const int iw = m0 + i * 16 + q * 4 + rr;  // w index
        const int d = j * 16 + l;
        O[(size_t)(r * 256 + iw) * 1024 + 512 + H * 64 + d] = f2b(acc[i][j][rr]);
      }
}

// ---------------- output projection with LDS staging: out = Ocat(32768x1024) @ W2 + bias ---
// XCD remap, n innermost: each m-panel's two n-tiles are dispatch-adjacent ->
// A-panel (256 KB) second read is L2-hot; each XCD owns 32 contiguous m-panels.
__global__ __launch_bounds__(256) void out_proj(const unsigned short* __restrict__ O,
                                                const unsigned short* __restrict__ W2T,
                                                const float* __restrict__ bw,
                                                const float* __restrict__ bh,
                                                float* __restrict__ out) {
  __shared__ unsigned short As[128 * 32];
  __shared__ unsigned short Bs[128 * 32];
  const int tid = threadIdx.x, wave = tid >> 6, lane = tid & 63;
  const int q = lane >> 4, l = lane & 15;
  const int xcd = blockIdx.x & 7;
  const int c = blockIdx.x >> 3;                  // 0..63 within XCD chunk
  const int m0 = (xcd * 32 + (c >> 1)) * 128;     // 32 m-panels per XCD
  const int n0 = (c & 1) * 128;                   // n innermost
  const int mt = (wave >> 1) * 64;
  const int nt = (wave & 1) * 64;
  const char* Ob = (const char*)O;
  const char* Wb = (const char*)W2T;
  const int srow = wave * 32 + (lane >> 2);
  const int sboff = (lane & 3) * 16;
  char* AsB = (char*)As;
  char* BsB = (char*)Bs;
  f32x4 acc[4][4] = {};
  for (int ks = 0; ks < 32; ++ks) {
    const int kb = ks * 64;  // byte offset within 2048-B row
    gld_lds16(Ob + (size_t)(m0 + srow) * 2048 + kb + sboff, AsB + wave * 2048);
    gld_lds16(Ob + (size_t)(m0 + srow + 16) * 2048 + kb + sboff, AsB + wave * 2048 + 1024);
    gld_lds16(Wb + (size_t)(n0 + srow) * 2048 + kb + sboff, BsB + wave * 2048);
    gld_lds16(Wb + (size_t)(n0 + srow + 16) * 2048 + kb + sboff, BsB + wave * 2048 + 1024);
    __syncthreads();
    s16x8 a[4], b[4];
#pragma unroll
    for (int i = 0; i < 4; ++i) a[i] = *(const s16x8*)(&As[(mt + i * 16 + l) * 32 + q * 8]);
#pragma unroll
    for (int j = 0; j < 4; ++j) b[j] = *(const s16x8*)(&Bs[(nt + j * 16 + l) * 32 + q * 8]);
#pragma unroll
    for (int i = 0; i < 4; ++i)
#pragma unroll
      for (int j = 0; j < 4; ++j) acc[i][j] = MFMA16(a[i], b[j], acc[i][j]);
    __syncthreads();
  }
#pragma unroll
  for (int i = 0; i < 4; ++i)
#pragma unroll
    for (int j = 0; j < 4; ++j) {
      const int col = n0 + nt + j * 16 + l;
      const float bias = bw[col] + bh[col];
#pragma unroll
      for (int r = 0; r < 4; ++r)
        out[(size_t)(m0 + mt + i * 16 + q * 4 + r) * 256 + col] = acc[i][j][r] + bias;
    }
}

extern "C" void kernel_launch(void* const* d_in, const int* in_sizes, int n_in,
                              void* d_out, int out_size, void* d_ws, size_t ws_size,
                              hipStream_t stream) {
  const float* x    = (const float*)d_in[0];
  const float* wq   = (const float*)d_in[1];
  const float* wkv  = (const float*)d_in[2];
  const float* wout = (const float*)d_in[3];
  const float* bw   = (const float*)d_in[4];
  const float* hq   = (const float*)d_in[5];
  const float* hkv  = (const float*)d_in[6];
  const float* hout = (const float*)d_in[7];
  const float* bh   = (const float*)d_in[8];
  float* out = (float*)d_out;

  char* ws = (char*)d_ws;
  unsigned short* x_bf  = (unsigned short*)(ws);               // 16 MB
  unsigned short* WcatT = (unsigned short*)(ws + 16777216);    // 1.5 MB
  unsigned short* W2T   = (unsigned short*)(ws + 18350080);    // 0.5 MB
  float*          dp    = (float*)(ws + 18874368);             // 16 MB
  unsigned short* attn  = (unsigned short*)(ws + 35651584);    // 1 MB
  unsigned short* Ocat  = (unsigned short*)(ws + 36700160);    // 64 MB
  unsigned short* Cproj0 = (unsigned short*)(ws + 103809024);  // 96 MB
  unsigned short* Cproj1 = (unsigned short*)(ws + 103809024 + 100663296);  // 96 MB (if room)
  const size_t need2 = 103809024 + 2ull * 100663296;

  cvt_x<<<8192, 256, 0, stream>>>(x, x_bf);
  build_wt<<<3072, 256, 0, stream>>>(wq, wkv, hq, hkv, WcatT);
  build_w2t<<<256, 256, 0, stream>>>(wout, hout, W2T);

  if (ws_size >= need2) {
    // merged: both branches in one dispatch, separate C buffers
    gemm_qkv2<<<6144, 512, 0, stream>>>(x_bf, WcatT, Cproj0, Cproj1);
    col_attn<<<dim3(256, 8), 256, 0, stream>>>(Cproj0, Ocat);
    row_dots<<<dim3(4, 8, 8), 256, 0, stream>>>(Cproj1, dp);
    row_softmax<<<2048, 256, 0, stream>>>(dp, attn);
    row_pv<<<dim3(128, 8), 256, 0, stream>>>(Cproj1, attn, Ocat);
  } else {
    // fallback (r13): sequential branches sharing Cproj0
    gemm_qkv<<<3072, 512, 0, stream>>>(x_bf, WcatT, Cproj0, 0);
    col_attn<<<dim3(256, 8), 256, 0, stream>>>(Cproj0, Ocat);
    gemm_qkv<<<3072, 512, 0, stream>>>(x_bf, WcatT + 1536 * 256, Cproj0, 1);
    row_dots<<<dim3(4, 8, 8), 256, 0, stream>>>(Cproj0, dp);
    row_softmax<<<2048, 256, 0, stream>>>(dp, attn);
    row_pv<<<dim3(128, 8), 256, 0, stream>>>(Cproj0, attn, Ocat);
  }
  out_proj<<<512, 256, 0, stream>>>(Ocat, W2T, bw, bh, out);
}

// Round 15
// 348.805 us; speedup vs baseline: 1.0099x; 1.0099x over previous
//
#include <hip/hip_runtime.h>

typedef short s16x8 __attribute__((ext_vector_type(8)));
typedef float f32x4 __attribute__((ext_vector_type(4)));

#define MFMA16(a, b, c) __builtin_amdgcn_mfma_f32_16x16x32_bf16((a), (b), (c), 0, 0, 0)

__device__ __forceinline__ unsigned short f2b(float f) {
  union { float f; unsigned int u; } v; v.f = f;
  unsigned int u = v.u;
  unsigned int r = (u + 0x7fffu + ((u >> 16) & 1u)) >> 16;  // RNE
  return (unsigned short)r;
}
__device__ __forceinline__ float b2f(unsigned short b) {
  union { unsigned int u; float f; } v; v.u = ((unsigned int)b) << 16;
  return v.f;
}

__device__ __forceinline__ void gld_lds16(const void* g, void* l) {
  __builtin_amdgcn_global_load_lds(
      (const __attribute__((address_space(1))) unsigned int*)g,
      (__attribute__((address_space(3))) unsigned int*)l, 16, 0, 0);
}

// ---------------- prep ----------------
__global__ __launch_bounds__(256) void cvt_x(const float* __restrict__ x,
                                             unsigned short* __restrict__ xb) {
  size_t i = ((size_t)blockIdx.x * 256 + threadIdx.x) * 4;
  float4 v = *(const float4*)(x + i);
  ushort4 o;
  o.x = f2b(v.x); o.y = f2b(v.y); o.z = f2b(v.z); o.w = f2b(v.w);
  *(ushort4*)(xb + i) = o;
}

// WcatT[n][k] = W[k][n], n in [0,3072): [wq | wkv | hq | hkv]
__global__ __launch_bounds__(256) void build_wt(const float* __restrict__ wq,
                                                const float* __restrict__ wkv,
                                                const float* __restrict__ hq,
                                                const float* __restrict__ hkv,
                                                unsigned short* __restrict__ WT) {
  const int n = blockIdx.x, k = threadIdx.x;
  float v;
  if (n < 512)       v = wq [(size_t)k * 512  + n];
  else if (n < 1536) v = wkv[(size_t)k * 1024 + (n - 512)];
  else if (n < 2048) v = hq [(size_t)k * 512  + (n - 1536)];
  else               v = hkv[(size_t)k * 1024 + (n - 2048)];
  WT[(size_t)n * 256 + k] = f2b(v);
}

// W2T[n][k] = [wout;hout][k][n], n<256, k<1024
__global__ __launch_bounds__(256) void build_w2t(const float* __restrict__ wout,
                                                 const float* __restrict__ hout,
                                                 unsigned short* __restrict__ W2T) {
  const int n = blockIdx.x;
  for (int k = threadIdx.x; k < 1024; k += 256) {
    const float v = (k < 512) ? wout[(size_t)k * 256 + n] : hout[(size_t)(k - 512) * 256 + n];
    W2T[(size_t)n * 1024 + k] = f2b(v);
  }
}

// ---------------- QKV projection: 4-deep pipelined staging, counted vmcnt ----------------
// T3/T4: prologue issues K-steps 0..3 into 4 LDS slots (8 loads/thread in flight).
// Per step: s_waitcnt vmcnt(N) (own step-k loads done; every wave waits -> after the
// raw s_barrier ALL step-k data is complete), compute, second barrier (all reads of
// the slot done), THEN issue step k+4 into that slot.  Loads for steps k+1..k+3 stay
// in flight across every barrier -- no vmcnt(0) drain except the final step.
// XCD remap (r11/r13): m-fastest within chunk.  8 light waves (r12): 32x64 tiles.
// MFMA operands SWAPPED (r4): lane holds 4 consecutive n for fixed m -> ushort4.
// C layout (per part q/k/v of 16777216 elems):
//   branch 0 (col attn): part + ((w*8+H)*128 + h)*64 + d     (slab = 128x64)
//   branch 1 (row attn): part + ((r*8+H)*256 + i)*64 + d     (slab = 256x64)
__global__ __launch_bounds__(512) void gemm_qkv(const unsigned short* __restrict__ X,
                                                const unsigned short* __restrict__ WT,
                                                unsigned short* __restrict__ C,
                                                int branch) {
  __shared__ unsigned short As[4][128 * 32];  // 32 KB
  __shared__ unsigned short Bs[4][128 * 32];  // 32 KB
  const int tid = threadIdx.x, wave = tid >> 6, lane = tid & 63;
  const int q = lane >> 4, l = lane & 15;
  const int xcd = blockIdx.x & 7;
  const int c = blockIdx.x >> 3;                  // 0..383 within XCD chunk
  const int m0 = (xcd * 32 + (c & 31)) * 128;     // m fastest within chunk
  const int n0 = (c >> 5) * 128;                  // 12 n-tiles
  const int mt = (wave >> 1) * 32;                // 4x2 wave grid, 32x64 tiles
  const int nt = (wave & 1) * 64;
  const char* Xb = (const char*)X;
  const char* Wb = (const char*)WT;
  const int srow = tid >> 2;                      // staging row (0..127)
  const int sboff = (tid & 3) * 16;
  f32x4 acc[2][4] = {};

#define QKV_STAGE(ks)                                                              \
  {                                                                                \
    const int kb_ = (ks) * 64;                                                     \
    gld_lds16(Xb + (size_t)(m0 + srow) * 512 + kb_ + sboff,                        \
              (char*)As[(ks) & 3] + tid * 16);                                     \
    gld_lds16(Wb + (size_t)(n0 + srow) * 512 + kb_ + sboff,                        \
              (char*)Bs[(ks) & 3] + tid * 16);                                     \
  }

#define QKV_STEP(ks, VM)                                                           \
  {                                                                                \
    asm volatile("s_waitcnt vmcnt(" #VM ")" ::: "memory");                         \
    __builtin_amdgcn_s_barrier();                                                  \
    __builtin_amdgcn_sched_barrier(0);                                             \
    s16x8 a[2], b[4];                                                              \
    _Pragma("unroll") for (int i = 0; i < 2; ++i)                                  \
        a[i] = *(const s16x8*)(&As[(ks) & 3][(mt + i * 16 + l) * 32 + q * 8]);     \
    _Pragma("unroll") for (int j = 0; j < 4; ++j)                                  \
        b[j] = *(const s16x8*)(&Bs[(ks) & 3][(nt + j * 16 + l) * 32 + q * 8]);     \
    _Pragma("unroll") for (int i = 0; i < 2; ++i)                                  \
        _Pragma("unroll") for (int j = 0; j < 4; ++j)                              \
            acc[i][j] = MFMA16(b[j], a[i], acc[i][j]); /* swapped: D^T */          \
    __builtin_amdgcn_s_barrier();                                                  \
    asm volatile("" ::: "memory"); /* keep next stage below the barrier */         \
  }

  QKV_STAGE(0);
  QKV_STAGE(1);
  QKV_STAGE(2);
  QKV_STAGE(3);
  QKV_STEP(0, 6) QKV_STAGE(4);
  QKV_STEP(1, 6) QKV_STAGE(5);
  QKV_STEP(2, 6) QKV_STAGE(6);
  QKV_STEP(3, 6) QKV_STAGE(7);
  QKV_STEP(4, 6);
  QKV_STEP(5, 4);
  QKV_STEP(6, 2);
  QKV_STEP(7, 0);
#undef QKV_STAGE
#undef QKV_STEP

  // epilogue (r4): lane (q,l) frag (i,j) holds m = m0+mt+i*16+l, n = n0+nt+j*16+q*4 .. +3
#pragma unroll
  for (int i = 0; i < 2; ++i) {
    const int m = m0 + mt + i * 16 + l;
    const int mrow = (branch == 0) ? ((m & 255) * 8) : ((m >> 8) * 8);
    const int mcol = (branch == 0) ? (m >> 8) : (m & 255);
    const int mdim = (branch == 0) ? 128 : 256;
#pragma unroll
    for (int j = 0; j < 4; ++j) {
      const int n = n0 + nt + j * 16 + q * 4;
      const int part = n >> 9, H = (n & 511) >> 6, d = n & 63;
      ushort4 o;
      o.x = f2b(acc[i][j][0]); o.y = f2b(acc[i][j][1]);
      o.z = f2b(acc[i][j][2]); o.w = f2b(acc[i][j][3]);
      unsigned short* base = C + (size_t)part * 16777216;
      const size_t idx = ((size_t)(mrow + H) * mdim + mcol) * 64 + d;
      *(ushort4*)(base + idx) = o;
    }
  }
}

// ---------------- column attention: one block per (w, H)  (r13, verified) ----------------
__global__ __launch_bounds__(256) void col_attn(const unsigned short* __restrict__ C,
                                                unsigned short* __restrict__ O) {
  __shared__ __align__(16) char lds[50176];  // [0,32768): Q|K then Sp ; [32768,...): Vt
  char* QK = lds;
  unsigned short* Vt = (unsigned short*)(lds + 32768);  // [64][136]
  const int w = blockIdx.x, H = blockIdx.y;
  const int tid = threadIdx.x, wave = tid >> 6, lane = tid & 63;
  const int q = lane >> 4, l = lane & 15;
  const size_t slab = (size_t)(w * 8 + H) * 8192;  // 128x64
  const unsigned short* Qs = C + slab;
  const unsigned short* Ks = C + 16777216 + slab;
  const unsigned short* Vs = C + 33554432 + slab;
  // stage Q (16 KB) + K (16 KB): LDS chunk (r,c) <- global chunk (r, c^(r&7))
#pragma unroll
  for (int it = 0; it < 8; ++it) {
    const int u = it * 256 + tid;            // 0..2047 16B-chunks
    const int half = u >> 10;                // 0=Q, 1=K
    const int vv = u & 1023;
    const int r = vv >> 3, ch = vv & 7;      // row 0..127, chunk 0..7
    const char* src = (const char*)(half ? Ks : Qs);
    gld_lds16(src + (size_t)r * 128 + ((ch ^ (r & 7)) * 16), QK + u * 16);
  }
  // stage V^T: Vt[d][j] = V[j][d]
  for (int u = tid; u < 1024; u += 256) {
    const int j = u >> 3, db = u & 7;
    s16x8 v = *(const s16x8*)(Vs + j * 64 + db * 8);
#pragma unroll
    for (int t = 0; t < 8; ++t) Vt[(db * 8 + t) * 136 + j] = v[t];
  }
  __syncthreads();  // Q,K,Vt ready
  const int m0 = wave * 32;
  f32x4 acc[2][8] = {};
#pragma unroll
  for (int ks = 0; ks < 2; ++ks) {
    s16x8 a[2], b[8];
#pragma unroll
    for (int i = 0; i < 2; ++i) {
      const int ra = m0 + i * 16 + l;
      a[i] = *(const s16x8*)(QK + (size_t)ra * 128 + (((ks * 4 + q) ^ (ra & 7)) * 16));
    }
#pragma unroll
    for (int j = 0; j < 8; ++j) {
      const int rb = j * 16 + l;
      b[j] = *(const s16x8*)(QK + 16384 + (size_t)rb * 128 + (((ks * 4 + q) ^ (rb & 7)) * 16));
    }
#pragma unroll
    for (int i = 0; i < 2; ++i)
#pragma unroll
      for (int j = 0; j < 8; ++j) acc[i][j] = MFMA16(a[i], b[j], acc[i][j]);
  }
  __syncthreads();  // all waves done reading Q/K -> region becomes Sp
#pragma unroll
  for (int i = 0; i < 2; ++i)
#pragma unroll
    for (int r = 0; r < 4; ++r) {
      float v[8];
#pragma unroll
      for (int j = 0; j < 8; ++j) v[j] = acc[i][j][r] * 0.125f;
      float mx = fmaxf(fmaxf(fmaxf(v[0], v[1]), fmaxf(v[2], v[3])),
                       fmaxf(fmaxf(v[4], v[5]), fmaxf(v[6], v[7])));
      mx = fmaxf(mx, __shfl_xor(mx, 1));
      mx = fmaxf(mx, __shfl_xor(mx, 2));
      mx = fmaxf(mx, __shfl_xor(mx, 4));
      mx = fmaxf(mx, __shfl_xor(mx, 8));
      float s = 0.f;
#pragma unroll
      for (int j = 0; j < 8; ++j) { v[j] = __expf(v[j] - mx); s += v[j]; }
      s += __shfl_xor(s, 1);
      s += __shfl_xor(s, 2);
      s += __shfl_xor(s, 4);
      s += __shfl_xor(s, 8);
      const float inv = 1.0f / s;
      const int row = m0 + i * 16 + q * 4 + r;
#pragma unroll
      for (int j = 0; j < 8; ++j) {
        const int ch = 2 * j + (l >> 3);  // 16B chunk of col j*16+l
        *(unsigned short*)(QK + (size_t)row * 256 + ((ch ^ (row & 7)) * 16) + (l & 7) * 2) =
            f2b(v[j] * inv);
      }
    }
  // Sp rows are wave-private; Vt covered by first barrier.
  f32x4 o[2][4] = {};
#pragma unroll
  for (int ks = 0; ks < 4; ++ks) {
    const int kk = ks * 32 + q * 8;
    s16x8 a[2], b[4];
#pragma unroll
    for (int i = 0; i < 2; ++i) {
      const int ra = m0 + i * 16 + l;
      a[i] = *(const s16x8*)(QK + (size_t)ra * 256 + (((ks * 4 + q) ^ (ra & 7)) * 16));
    }
#pragma unroll
    for (int j = 0; j < 4; ++j) b[j] = *(const s16x8*)(&Vt[(j * 16 + l) * 136 + kk]);
#pragma unroll
    for (int i = 0; i < 2; ++i)
#pragma unroll
      for (int j = 0; j < 4; ++j) o[i][j] = MFMA16(a[i], b[j], o[i][j]);
  }
#pragma unroll
  for (int i = 0; i < 2; ++i)
#pragma unroll
    for (int j = 0; j < 4; ++j)
#pragma unroll
      for (int r = 0; r < 4; ++r) {
        const int row = m0 + i * 16 + q * 4 + r;  // seq pos (h index)
        const int d = j * 16 + l;
        O[(size_t)(row * 256 + w) * 1024 + H * 64 + d] = f2b(o[i][j][r]);
      }
}

// ---------------- tied row attention dots, split-K over 8 chunks of 16 rows ----------------
__global__ __launch_bounds__(256) void row_dots(const unsigned short* __restrict__ C,
                                                float* __restrict__ dp) {
  const int H = blockIdx.z;
  const int r0 = blockIdx.y * 16;
  const int ti = blockIdx.x & 1, tj = blockIdx.x >> 1;
  const int tid = threadIdx.x, wave = tid >> 6, lane = tid & 63;
  const int q = lane >> 4, l = lane & 15;
  const int m0 = ti * 128 + (wave >> 1) * 64;
  const int n0 = tj * 128 + (wave & 1) * 64;
  const unsigned short* Qh = C;
  const unsigned short* Kh = C + 16777216;
  f32x4 acc[4][4] = {};
  for (int ks = 0; ks < 32; ++ks) {
    const int k = ks * 32 + q * 8;
    const int rr = r0 + (k >> 6), d = k & 63;
    const size_t slab = (size_t)(rr * 8 + H) * 16384;  // 256x64
    s16x8 a[4], b[4];
#pragma unroll
    for (int i = 0; i < 4; ++i) a[i] = *(const s16x8*)(Qh + slab + (m0 + i * 16 + l) * 64 + d);
#pragma unroll
    for (int j = 0; j < 4; ++j) b[j] = *(const s16x8*)(Kh + slab + (n0 + j * 16 + l) * 64 + d);
#pragma unroll
    for (int i = 0; i < 4; ++i)
#pragma unroll
      for (int j = 0; j < 4; ++j) acc[i][j] = MFMA16(a[i], b[j], acc[i][j]);
  }
  float* outp = dp + ((size_t)blockIdx.y * 8 + H) * 65536;
#pragma unroll
  for (int i = 0; i < 4; ++i)
#pragma unroll
    for (int j = 0; j < 4; ++j)
#pragma unroll
      for (int r = 0; r < 4; ++r)
        outp[(size_t)(m0 + i * 16 + q * 4 + r) * 256 + n0 + j * 16 + l] = acc[i][j][r];
}

__global__ __launch_bounds__(256) void row_softmax(const float* __restrict__ dp,
                                                   unsigned short* __restrict__ attn) {
  const int row = blockIdx.x;  // H*256 + i
  const int H = row >> 8, i = row & 255;
  const int t = threadIdx.x, wave = t >> 6, lane = t & 63;
  __shared__ float red[8];
  float v = 0.f;
#pragma unroll
  for (int c = 0; c < 8; ++c) v += dp[((size_t)c * 8 + H) * 65536 + (size_t)i * 256 + t];
  v *= 1.1048543456e-2f;  // 0.125 / sqrt(128)
  float m = v;
  for (int o = 32; o > 0; o >>= 1) m = fmaxf(m, __shfl_xor(m, o, 64));
  if (lane == 0) red[wave] = m;
  __syncthreads();
  const float M = fmaxf(fmaxf(red[0], red[1]), fmaxf(red[2], red[3]));
  const float e = __expf(v - M);
  float s = e;
  for (int o = 32; o > 0; o >>= 1) s += __shfl_xor(s, o, 64);
  if (lane == 0) red[4 + wave] = s;
  __syncthreads();
  const float S = red[4] + red[5] + red[6] + red[7];
  attn[(size_t)row * 256 + t] = f2b(e / S);
}

// ---------------- row attention PV: one block per (r, H) ----------------
__global__ __launch_bounds__(256) void row_pv(const unsigned short* __restrict__ C,
                                              const unsigned short* __restrict__ attn,
                                              unsigned short* __restrict__ O) {
  __shared__ unsigned short Vt[64 * 264];
  const int r = blockIdx.x, H = blockIdx.y;
  const int tid = threadIdx.x, wave = tid >> 6, lane = tid & 63;
  const int q = lane >> 4, l = lane & 15;
  const unsigned short* Vs = C + 33554432 + (size_t)(r * 8 + H) * 16384;
  for (int u = tid; u < 2048; u += 256) {
    const int j = u >> 3, db = u & 7;
    s16x8 v = *(const s16x8*)(Vs + j * 64 + db * 8);
#pragma unroll
    for (int t = 0; t < 8; ++t) Vt[(db * 8 + t) * 264 + j] = v[t];
  }
  __syncthreads();
  const unsigned short* A = attn + (size_t)H * 65536;
  const int m0 = wave * 64;
  f32x4 acc[4][4] = {};
#pragma unroll
  for (int ks = 0; ks < 8; ++ks) {
    const int kk = ks * 32 + q * 8;
    s16x8 a[4], b[4];
#pragma unroll
    for (int i = 0; i < 4; ++i) a[i] = *(const s16x8*)(A + (size_t)(m0 + i * 16 + l) * 256 + kk);
#pragma unroll
    for (int j = 0; j < 4; ++j) b[j] = *(const s16x8*)(&Vt[(j * 16 + l) * 264 + kk]);
#pragma unroll
    for (int i = 0; i < 4; ++i)
#pragma unroll
      for (int j = 0; j < 4; ++j) acc[i][j] = MFMA16(a[i], b[j], acc[i][j]);
  }
#pragma unroll
  for (int i = 0; i < 4; ++i)
#pragma unroll
    for (int j = 0; j < 4; ++j)
#pragma unroll
      for (int rr = 0; rr < 4; ++rr) {
        const int iw = m0 + i * 16 + q * 4 + rr;  // w index
        const int d = j * 16 + l;
        O[(size_t)(r * 256 + iw) * 1024 + 512 + H * 64 + d] = f2b(acc[i][j][rr]);
      }
}

// ---------------- output projection with LDS staging: out = Ocat(32768x1024) @ W2 + bias ----------------
__global__ __launch_bounds__(256) void out_proj(const unsigned short* __restrict__ O,
                                                const unsigned short* __restrict__ W2T,
                                                const float* __restrict__ bw,
                                                const float* __restrict__ bh,
                                                float* __restrict__ out) {
  __shared__ unsigned short As[128 * 32];
  __shared__ unsigned short Bs[128 * 32];
  const int tid = threadIdx.x, wave = tid >> 6, lane = tid & 63;
  const int q = lane >> 4, l = lane & 15;
  const int m0 = blockIdx.x * 128;
  const int n0 = blockIdx.y * 128;
  const int mt = (wave >> 1) * 64;
  const int nt = (wave & 1) * 64;
  const char* Ob = (const char*)O;
  const char* Wb = (const char*)W2T;
  const int srow = wave * 32 + (lane >> 2);
  const int sboff = (lane & 3) * 16;
  char* AsB = (char*)As;
  char* BsB = (char*)Bs;
  f32x4 acc[4][4] = {};
  for (int ks = 0; ks < 32; ++ks) {
    const int kb = ks * 64;  // byte offset within 2048-B row
    gld_lds16(Ob + (size_t)(m0 + srow) * 2048 + kb + sboff, AsB + wave * 2048);
    gld_lds16(Ob + (size_t)(m0 + srow + 16) * 2048 + kb + sboff, AsB + wave * 2048 + 1024);
    gld_lds16(Wb + (size_t)(n0 + srow) * 2048 + kb + sboff, BsB + wave * 2048);
    gld_lds16(Wb + (size_t)(n0 + srow + 16) * 2048 + kb + sboff, BsB + wave * 2048 + 1024);
    __syncthreads();
    s16x8 a[4], b[4];
#pragma unroll
    for (int i = 0; i < 4; ++i) a[i] = *(const s16x8*)(&As[(mt + i * 16 + l) * 32 + q * 8]);
#pragma unroll
    for (int j = 0; j < 4; ++j) b[j] = *(const s16x8*)(&Bs[(nt + j * 16 + l) * 32 + q * 8]);
#pragma unroll
    for (int i = 0; i < 4; ++i)
#pragma unroll
      for (int j = 0; j < 4; ++j) acc[i][j] = MFMA16(a[i], b[j], acc[i][j]);
    __syncthreads();
  }
#pragma unroll
  for (int i = 0; i < 4; ++i)
#pragma unroll
    for (int j = 0; j < 4; ++j) {
      const int col = n0 + nt + j * 16 + l;
      const float bias = bw[col] + bh[col];
#pragma unroll
      for (int r = 0; r < 4; ++r)
        out[(size_t)(m0 + mt + i * 16 + q * 4 + r) * 256 + col] = acc[i][j][r] + bias;
    }
}

extern "C" void kernel_launch(void* const* d_in, const int* in_sizes, int n_in,
                              void* d_out, int out_size, void* d_ws, size_t ws_size,
                              hipStream_t stream) {
  const float* x    = (const float*)d_in[0];
  const float* wq   = (const float*)d_in[1];
  const float* wkv  = (const float*)d_in[2];
  const float* wout = (const float*)d_in[3];
  const float* bw   = (const float*)d_in[4];
  const float* hq   = (const float*)d_in[5];
  const float* hkv  = (const float*)d_in[6];
  const float* hout = (const float*)d_in[7];
  const float* bh   = (const float*)d_in[8];
  float* out = (float*)d_out;

  char* ws = (char*)d_ws;
  unsigned short* x_bf  = (unsigned short*)(ws);               // 16 MB
  unsigned short* WcatT = (unsigned short*)(ws + 16777216);    // 1.5 MB
  unsigned short* W2T   = (unsigned short*)(ws + 18350080);    // 0.5 MB
  float*          dp    = (float*)(ws + 18874368);             // 16 MB
  unsigned short* attn  = (unsigned short*)(ws + 35651584);    // 1 MB
  unsigned short* Ocat  = (unsigned short*)(ws + 36700160);    // 64 MB
  unsigned short* Cproj = (unsigned short*)(ws + 103809024);   // 96 MB (reused per branch)

  cvt_x<<<8192, 256, 0, stream>>>(x, x_bf);
  build_wt<<<3072, 256, 0, stream>>>(wq, wkv, hq, hkv, WcatT);
  build_w2t<<<256, 256, 0, stream>>>(wout, hout, W2T);

  // w-branch (column attention)
  gemm_qkv<<<3072, 512, 0, stream>>>(x_bf, WcatT, Cproj, 0);
  col_attn<<<dim3(256, 8), 256, 0, stream>>>(Cproj, Ocat);
  // h-branch (tied row attention), reuses Cproj
  gemm_qkv<<<3072, 512, 0, stream>>>(x_bf, WcatT + 1536 * 256, Cproj, 1);
  row_dots<<<dim3(4, 8, 8), 256, 0, stream>>>(Cproj, dp);
  row_softmax<<<2048, 256, 0, stream>>>(dp, attn);
  row_pv<<<dim3(128, 8), 256, 0, stream>>>(Cproj, attn, Ocat);
  out_proj<<<dim3(256, 2), 256, 0, stream>>>(Ocat, W2T, bw, bh, out);
}